// Round 1
// 493.321 us; speedup vs baseline: 1.0618x; 1.0618x over previous
//
#include <hip/hip_runtime.h>

#define S_LEN 4096
#define D_HEAD 64
#define NH 16
#define C_DIM 1024
#define B_SZ 16
#define NG 256                    // B*H groups
#define NSPLIT 8
#define CHUNK (S_LEN / NSPLIT)    // 512 rows per block
#define TPB 256
#define RG 16                     // row-groups per block (16 lanes each)
#define ITERS (CHUNK / RG)        // 32

typedef float f4 __attribute__((ext_vector_type(4)));

// ---------------------------------------------------------------------------
// Kernel 0: normalize q and pre-apply softmax scale: qs = q/||q|| * 0.125
// ---------------------------------------------------------------------------
__global__ __launch_bounds__(256) void qnorm_kernel(
    const float* __restrict__ q, float* __restrict__ qs)
{
    const int tid = threadIdx.x;
    float v[4];
    float p = 0.f;
    #pragma unroll
    for (int i = 0; i < 4; i++) {
        v[i] = q[tid + i * 256];
        p += v[i] * v[i];
    }
    #pragma unroll
    for (int off = 32; off; off >>= 1) p += __shfl_xor(p, off);
    __shared__ float red[4];
    if ((tid & 63) == 0) red[tid >> 6] = p;
    __syncthreads();
    const float total = red[0] + red[1] + red[2] + red[3];
    const float s = rsqrtf(total) * 0.125f;   // 1/||q|| * 1/sqrt(64)
    #pragma unroll
    for (int i = 0; i < 4; i++) qs[tid + i * 256] = v[i] * s;
}

// ---------------------------------------------------------------------------
// Kernel 1: flash-decode partial attention, SINGLE-PASS online softmax.
// One block per (group, split). Each 16-lane row-group walks its 32 rows
// keeping a running (m, l, acc) — no barriers in the streaming loop, K and
// V read together (interleaved streams), nontemporal (zero-reuse data).
// One end-of-block LDS merge of the 16 row-group partials.
// 2048 blocks x 256 threads -> 8 blocks/CU target.
// ---------------------------------------------------------------------------
__global__ __launch_bounds__(TPB) void attn_partial(
    const float* __restrict__ K, const float* __restrict__ V,
    const float* __restrict__ qs, float* __restrict__ Apart,
    float* __restrict__ mArr, float* __restrict__ lArr)
{
    const int blk   = blockIdx.x;
    const int g     = blk >> 3;       // group 0..255
    const int split = blk & 7;        // chunk 0..7
    const int h     = g & (NH - 1);
    const int tid   = threadIdx.x;
    const int sub   = tid & 15;       // float4 index within 64-dim row
    const int rg    = tid >> 4;       // row-group 0..15

    __shared__ __align__(16) float part[RG * D_HEAD]; // 4 KB row-group partials
    __shared__ float mS[RG];
    __shared__ float lS[RG];

    const f4 qv = ((const f4*)(qs + h * D_HEAD))[sub];
    const f4* __restrict__ Kg =
        (const f4*)(K + ((size_t)g * S_LEN + (size_t)split * CHUNK) * D_HEAD);
    const f4* __restrict__ Vg =
        (const f4*)(V + ((size_t)g * S_LEN + (size_t)split * CHUNK) * D_HEAD);

    float m = -3.4e38f;
    float l = 0.f;
    f4 acc = (f4){0.f, 0.f, 0.f, 0.f};

    // ---- single streaming pass: dot, online-softmax update, V accumulate ----
    #pragma unroll 4
    for (int i = 0; i < ITERS; i++) {
        const int r = rg + i * RG;
        const f4 kv = __builtin_nontemporal_load(Kg + r * (D_HEAD / 4) + sub);
        const f4 vv = __builtin_nontemporal_load(Vg + r * (D_HEAD / 4) + sub);
        float d = kv.x * qv.x + kv.y * qv.y + kv.z * qv.z + kv.w * qv.w;
        d += __shfl_xor(d, 1);
        d += __shfl_xor(d, 2);
        d += __shfl_xor(d, 4);
        d += __shfl_xor(d, 8);                  // all 16 lanes hold the row score
        const float mnew = fmaxf(m, d);
        const float fsc  = __expf(m - mnew);    // rescale factor (==1 typically)
        const float w    = __expf(d - mnew);    // this row's weight
        l   = l * fsc + w;
        acc = acc * fsc + w * vv;
        m   = mnew;
    }

    // ---- end-of-block merge of 16 row-group partials ----
    ((f4*)part)[rg * 16 + sub] = acc;
    if (sub == 0) { mS[rg] = m; lS[rg] = l; }
    __syncthreads();

    if (tid < D_HEAD) {
        float M = mS[0];
        #pragma unroll
        for (int r2 = 1; r2 < RG; r2++) M = fmaxf(M, mS[r2]);
        float s = 0.f, lt = 0.f;
        #pragma unroll
        for (int r2 = 0; r2 < RG; r2++) {
            const float f = __expf(mS[r2] - M);
            s  += f * part[r2 * D_HEAD + tid];   // lanes consecutive: conflict-free
            lt += f * lS[r2];
        }
        Apart[(size_t)blk * D_HEAD + tid] = s;
        if (tid == 0) { mArr[blk] = M; lArr[blk] = lt; }
    }
}

// ---------------------------------------------------------------------------
// Kernel 2: online-softmax merge of the 8 splits per group.
// ---------------------------------------------------------------------------
__global__ __launch_bounds__(64) void attn_combine(
    const float* __restrict__ Apart, const float* __restrict__ mArr,
    const float* __restrict__ lArr, float* __restrict__ A)
{
    const int g = blockIdx.x;
    const int d = threadIdx.x;
    float mv[NSPLIT];
    float M = -3.4e38f;
    #pragma unroll
    for (int s = 0; s < NSPLIT; s++) {
        mv[s] = mArr[g * NSPLIT + s];
        M = fmaxf(M, mv[s]);
    }
    float denom = 0.f, acc = 0.f;
    #pragma unroll
    for (int s = 0; s < NSPLIT; s++) {
        const float f = __expf(mv[s] - M);
        denom += f * lArr[g * NSPLIT + s];
        acc   += f * Apart[(size_t)(g * NSPLIT + s) * D_HEAD + d];
    }
    A[g * D_HEAD + d] = acc / denom;   // layout == A_full[b][h*64+d]
}

// ---------------------------------------------------------------------------
// Kernel 3: Y[b,j] = dot(A[b,:], W[j,:]) + bias[j]. One block per column j.
// ---------------------------------------------------------------------------
__global__ __launch_bounds__(256) void proj_kernel(
    const float* __restrict__ A, const float* __restrict__ W,
    const float* __restrict__ bias, float* __restrict__ Y)
{
    const int j = blockIdx.x;
    const int tid = threadIdx.x;
    const float* __restrict__ Wj = W + (size_t)j * C_DIM;

    float acc[B_SZ];
    #pragma unroll
    for (int b = 0; b < B_SZ; b++) acc[b] = 0.f;

    #pragma unroll
    for (int k = 0; k < 4; k++) {
        const int c = tid + k * 256;
        const float w = Wj[c];
        #pragma unroll
        for (int b = 0; b < B_SZ; b++) acc[b] += A[b * C_DIM + c] * w;
    }

    __shared__ float redw[B_SZ][4];
    #pragma unroll
    for (int b = 0; b < B_SZ; b++) {
        float v = acc[b];
        #pragma unroll
        for (int off = 32; off; off >>= 1) v += __shfl_xor(v, off);
        if ((tid & 63) == 0) redw[b][tid >> 6] = v;
    }
    __syncthreads();
    if (tid < B_SZ) {
        const float s = redw[tid][0] + redw[tid][1] + redw[tid][2] + redw[tid][3];
        Y[tid * C_DIM + j] = s + bias[j];
    }
}

// ---------------------------------------------------------------------------
// Kernel 4: LayerNorm over last dim (1024) per batch row.
// ---------------------------------------------------------------------------
__global__ __launch_bounds__(256) void ln_kernel(
    const float* __restrict__ Y, const float* __restrict__ gam,
    const float* __restrict__ bet, float* __restrict__ out)
{
    const int b = blockIdx.x;
    const int tid = threadIdx.x;
    const float* __restrict__ Yb = Y + b * C_DIM;

    float vals[4];
    float s = 0.f, s2 = 0.f;
    #pragma unroll
    for (int i = 0; i < 4; i++) {
        const float v = Yb[tid + i * 256];
        vals[i] = v;
        s += v;
        s2 += v * v;
    }
    #pragma unroll
    for (int off = 32; off; off >>= 1) {
        s  += __shfl_xor(s, off);
        s2 += __shfl_xor(s2, off);
    }
    __shared__ float rs[4], rs2[4];
    if ((tid & 63) == 0) { rs[tid >> 6] = s; rs2[tid >> 6] = s2; }
    __syncthreads();
    s  = rs[0] + rs[1] + rs[2] + rs[3];
    s2 = rs2[0] + rs2[1] + rs2[2] + rs2[3];
    const float mu  = s * (1.0f / C_DIM);
    const float var = s2 * (1.0f / C_DIM) - mu * mu;
    const float inv = rsqrtf(var + 1e-5f);
    #pragma unroll
    for (int i = 0; i < 4; i++) {
        const int j = tid + i * 256;
        out[b * C_DIM + j] = gam[j] * (vals[i] - mu) * inv + bet[j];
    }
}

extern "C" void kernel_launch(void* const* d_in, const int* in_sizes, int n_in,
                              void* d_out, int out_size, void* d_ws, size_t ws_size,
                              hipStream_t stream) {
    const float* K    = (const float*)d_in[0];
    const float* V    = (const float*)d_in[1];
    const float* q    = (const float*)d_in[2];
    const float* w0_w = (const float*)d_in[3];
    const float* w0_b = (const float*)d_in[4];
    const float* ln_g = (const float*)d_in[5];
    const float* ln_b = (const float*)d_in[6];

    float* qs    = (float*)d_ws;                      // 1024
    float* Apart = qs + C_DIM;                        // 2048*64 = 131072
    float* mArr  = Apart + (size_t)NG * NSPLIT * D_HEAD; // 2048
    float* lArr  = mArr + NG * NSPLIT;                // 2048
    float* A     = lArr + NG * NSPLIT;                // 16384
    float* Y     = A + B_SZ * C_DIM;                  // 16384

    qnorm_kernel<<<1, 256, 0, stream>>>(q, qs);
    attn_partial<<<NG * NSPLIT, TPB, 0, stream>>>(K, V, qs, Apart, mArr, lArr);
    attn_combine<<<NG, 64, 0, stream>>>(Apart, mArr, lArr, A);
    proj_kernel<<<C_DIM, 256, 0, stream>>>(A, w0_w, w0_b, Y);
    ln_kernel<<<B_SZ, 256, 0, stream>>>(Y, ln_g, ln_b, (float*)d_out);
}